// Round 3
// baseline (357.882 us; speedup 1.0000x reference)
//
#include <hip/hip_runtime.h>
#include <stdint.h>

#define N_ROWS 32768
#define K_CODES 8192
#define D_DIM 256
#define STEP_BYTES 33024   // 32 KiB bf16 codes + 256 B fp32 c2 table (16B-aligned)
#define NBUF 4

typedef __attribute__((ext_vector_type(8))) short short8;
typedef __attribute__((ext_vector_type(4))) float f32x4;

__device__ __forceinline__ unsigned short f2bf_rne(float f) {
  union { float f; unsigned u; } v; v.f = f;
  unsigned r = v.u + 0x7fffu + ((v.u >> 16) & 1u);
  return (unsigned short)(r >> 16);
}

// ---------------------------------------------------------------------------
// Prep: codebook fp32 -> bf16 (RNE), XOR-swizzled within each 512B row.
// Each 64-code step tile carries a 256 B fp32 |e|^2 table (exact c2).
// Zeroes counts.
// ---------------------------------------------------------------------------
__global__ __launch_bounds__(256) void eprep_kernel(
    const float* __restrict__ cb, unsigned short* __restrict__ ehw,
    int* __restrict__ counts) {
  int w = threadIdx.x >> 6, lane = threadIdx.x & 63;
  int k = blockIdx.x * 4 + w;
  int gid = blockIdx.x * 256 + threadIdx.x;
  if (gid < K_CODES) counts[gid] = 0;
  const float4* src = (const float4*)(cb + (size_t)k * D_DIM);
  float4 v = src[lane];
  float vv[4] = {v.x, v.y, v.z, v.w};
  unsigned short h[4];
  float s = 0.f;
#pragma unroll
  for (int j = 0; j < 4; ++j) {
    float f = vv[j];
    s += f * f;
    h[j] = f2bf_rne(f);
  }
  char* stepb = (char*)ehw + (size_t)(k >> 6) * STEP_BYTES;
  int cl = k & 63;
  int off = (8 * lane) ^ ((k & 7) << 4);  // swizzle flips bits 4-6 only
  *(ushort4*)(stepb + cl * 512 + off) = make_ushort4(h[0], h[1], h[2], h[3]);
#pragma unroll
  for (int m = 1; m < 64; m <<= 1) s += __shfl_xor(s, m);
  if (lane == 0) *(float*)(stepb + 32768 + cl * 4) = s;  // fp32-exact |e|^2
}

// ---------------------------------------------------------------------------
// Argmin, T3+T4 counted-vmcnt pipeline (depth 3, 4 LDS buffers).
// R3 revision — enc zero-fill is now FULL-LINE ALIGNED:
//   enc sits at byte 8 (mod 128), so the old 512B dwordx2 nt stores each
//   spanned 2 partial cache lines -> RMW at the memory side (~40% below the
//   proven write ceiling; R0's aligned dwordx4 fill hit 6.1 TB/s on the same
//   buffer). Now: per-block region [S, S+4MiB) is head 120 B + tail 8 B
//   (epilogue scalar stores) + 128B-aligned bulk of plain dwordx4 stores
//   (4 per wave per iter, full lines only, L2-merged).
// vmcnt stream: 5 loads + 4 stores per iter -> uniform wait vmcnt(18);
// tails 18/13/4. Final bulk unit is 120 B short: last store of wave 7 in
// peeled iter 125 is exec-predicated to lanes<56.
// 256 blocks x 128 rows; 8 waves = 2 row-groups x 4 code-groups.
// ---------------------------------------------------------------------------
__global__ __launch_bounds__(512, 1) void argmin_kernel(
    const float* __restrict__ x, const float* __restrict__ cb,
    const unsigned short* __restrict__ ehw,
    float* __restrict__ quant, int* __restrict__ counts,
    float* __restrict__ ssep, float* __restrict__ enc) {
  __shared__ __align__(16) char s_tiles[NBUF * STEP_BYTES];  // 129 KiB
  __shared__ float s_x2[128];
  __shared__ float s_red[128];
  // epilogue-only arrays aliased onto s_tiles (buf0 dead after the loop):
  float (*s_mn)[128] = (float (*)[128])(s_tiles);          // 2 KiB
  int (*s_mi)[128] = (int (*)[128])(s_tiles + 2048);       // 2 KiB

  const int tid = threadIdx.x;
  const int abid = blockIdx.x;
  const int ww = tid >> 6;
  const int lane = tid & 63;
  const int l15 = lane & 15;
  const int kg = lane >> 4;
  const int rg = ww >> 2;             // row group (0..1), 64 rows each
  const int cg = ww & 3;              // code group (0..3), 16 codes each
  const int row0 = abid * 128;

  auto STAGE = [&](int i, int b) {
    const char* g0 = (const char*)ehw + (size_t)i * STEP_BYTES + ww * 4096 + lane * 16;
    char* l0 = s_tiles + b * STEP_BYTES + ww * 4096;  // wave-uniform base
#pragma unroll
    for (int j = 0; j < 4; ++j) {
      __builtin_amdgcn_global_load_lds(
          (const __attribute__((address_space(1))) unsigned int*)(g0 + j * 1024),
          (__attribute__((address_space(3))) unsigned int*)(l0 + j * 1024), 16, 0, 0);
    }
    // c2 table: 256 B; ALL 8 waves load it redundantly (same data, same dest)
    // so every wave's vmcnt stream is a uniform 5 loads per stage.
    const char* g1 = (const char*)ehw + (size_t)i * STEP_BYTES + 32768 + lane * 4;
    char* l1 = s_tiles + b * STEP_BYTES + 32768;
    __builtin_amdgcn_global_load_lds(
        (const __attribute__((address_space(1))) unsigned int*)g1,
        (__attribute__((address_space(3))) unsigned int*)l1, 4, 0, 0);
  };

  // Aligned zero-fill bulk: unit u (u=0..127) = 32 KiB at S+120 + u*32768,
  // wave ww covers 4 KiB as 4 x dwordx4 (16 B/lane, full 128B lines).
  const f32x4 z4 = {0.f, 0.f, 0.f, 0.f};
  char* Sp = (char*)enc + (size_t)row0 * 32768;           // block region start
  char* zb = Sp + 120 + ww * 4096 + lane * 16;            // aligned bulk base
  auto ZST4 = [&](const char* p) {  // prologue burst form (4 stores)
    asm volatile(
        "global_store_dwordx4 %0, %1, off\n\t"
        "global_store_dwordx4 %0, %1, off offset:1024\n\t"
        "global_store_dwordx4 %0, %1, off offset:2048\n\t"
        "global_store_dwordx4 %0, %1, off offset:3072"
        :: "v"(p), "v"(z4));
  };

  // prologue: S0 Z0 S1 Z1 S2 — uniform vmcnt(18) from iter 0.
  STAGE(0, 0); ZST4(zb); STAGE(1, 1); ZST4(zb + 32768); STAGE(2, 2);

  // load & convert A fragments: 64 rows/wave (4 subtiles of 16), bf16
  short8 a_h[4][8];
  float x2acc[4];
#pragma unroll
  for (int s = 0; s < 4; ++s) {
    const float* rp = x + (size_t)(row0 + rg * 64 + s * 16 + l15) * D_DIM + kg * 8;
    float s2 = 0.f;
#pragma unroll
    for (int ch = 0; ch < 8; ++ch) {
      const float4* p = (const float4*)(rp + ch * 32);
      float4 v0 = p[0], v1 = p[1];
      float f[8] = {v0.x, v0.y, v0.z, v0.w, v1.x, v1.y, v1.z, v1.w};
#pragma unroll
      for (int j = 0; j < 8; ++j) {
        s2 += f[j] * f[j];
        a_h[s][ch][j] = (short)f2bf_rne(f[j]);
      }
    }
    x2acc[s] = s2;
  }
#pragma unroll
  for (int s = 0; s < 4; ++s) {
    x2acc[s] += __shfl_xor(x2acc[s], 16);
    x2acc[s] += __shfl_xor(x2acc[s], 32);
  }
  if (cg == 0 && lane < 16) {  // kg==0 lanes
#pragma unroll
    for (int s = 0; s < 4; ++s) s_x2[rg * 64 + s * 16 + l15] = x2acc[s];
  }

  float mn[16];
  int mi[16];
#pragma unroll
  for (int s = 0; s < 16; ++s) { mn[s] = 3.4e38f; mi[s] = 0x7fffffff; }

  const int c_local = cg * 16 + l15;     // lane's code within the 64-code step
  const int rb = c_local * 512;
  const int xm = (l15 & 7) << 4;         // (code&7)<<4

  // COMPUTE: preload 8 vh (ds_read_b128) + scalar c2 (ds_read_b32 broadcast),
  // then 8 x [4 MFMA], with one aligned dwordx4 zero-store on even channels.
  // stmode: 0 = no stores, 1 = 4 stores, 2 = 4 stores w/ last predicated
  // (final unit is 120 B short -> wave 7 lanes 56..63 skip store j=3).
  auto COMPUTE = [&](int t, int stmode, const char* sp) {
    const char* bh = s_tiles + (t & 3) * STEP_BYTES;
    const int code = t * 64 + c_local;
    const float c2 = *(const float*)(bh + 32768 + c_local * 4);
    short8 vh[8];
#pragma unroll
    for (int ch = 0; ch < 8; ++ch)
      vh[ch] = *(const short8*)(bh + rb + ((ch * 64 + kg * 16) ^ xm));
    f32x4 acc[4];
#pragma unroll
    for (int s = 0; s < 4; ++s) acc[s] = (f32x4){0.f, 0.f, 0.f, 0.f};
#pragma unroll
    for (int ch = 0; ch < 8; ++ch) {
      if (stmode && (ch & 1) == 0) {
        const int j = ch >> 1;
        if (stmode == 1 || j < 3 || ww < 7 || lane < 56) {
          asm volatile("global_store_dwordx4 %0, %1, off"
                       :: "v"(sp + j * 1024), "v"(z4));
        }
      }
      acc[0] = __builtin_amdgcn_mfma_f32_16x16x32_bf16(a_h[0][ch], vh[ch], acc[0], 0, 0, 0);
      acc[1] = __builtin_amdgcn_mfma_f32_16x16x32_bf16(a_h[1][ch], vh[ch], acc[1], 0, 0, 0);
      acc[2] = __builtin_amdgcn_mfma_f32_16x16x32_bf16(a_h[2][ch], vh[ch], acc[2], 0, 0, 0);
      acc[3] = __builtin_amdgcn_mfma_f32_16x16x32_bf16(a_h[3][ch], vh[ch], acc[3], 0, 0, 0);
    }
#pragma unroll
    for (int s = 0; s < 4; ++s) {
#pragma unroll
      for (int r = 0; r < 4; ++r) {
        float d = __builtin_fmaf(-2.f, acc[s][r], c2);   // |e|^2 - 2 x.e
        if (d < mn[s * 4 + r]) { mn[s * 4 + r] = d; mi[s * 4 + r] = code; }
      }
    }
  };

  // iter t (0..124): zeroes unit t+2, stages tile t+3.
  // wait needs S_t done; younger ops = 2 iters x (4S+5L) = 18.
#pragma unroll 1
  for (int t = 0; t < 125; ++t) {
    asm volatile("s_waitcnt vmcnt(18)" ::: "memory");
    __builtin_amdgcn_s_barrier();
    __builtin_amdgcn_sched_barrier(0);
    COMPUTE(t, 1, zb + (size_t)(t + 2) * 32768);
    STAGE(t + 3, (t + 3) & 3);  // overwrites buf (t-1)&3: readers done at barrier
  }
  // t=125: zeroes final unit 127 (predicated last store), no stage.
  // younger than S125 = iters 123,124 = 18.
  asm volatile("s_waitcnt vmcnt(18)" ::: "memory");
  __builtin_amdgcn_s_barrier();
  __builtin_amdgcn_sched_barrier(0);
  COMPUTE(125, 2, zb + (size_t)127 * 32768);
  // t=126: younger than S126 = iter124 (9) + Z125 (4) = 13.
  asm volatile("s_waitcnt vmcnt(13)" ::: "memory");
  __builtin_amdgcn_s_barrier();
  __builtin_amdgcn_sched_barrier(0);
  COMPUTE(126, 0, zb);
  // t=127: younger than S127 = Z125 (4).
  asm volatile("s_waitcnt vmcnt(4)" ::: "memory");
  __builtin_amdgcn_s_barrier();
  __builtin_amdgcn_sched_barrier(0);
  COMPUTE(127, 0, zb);

  // head 120 B + tail 8 B of the block's enc region (mod-128 remainders)
  if (tid < 30) ((float*)Sp)[tid] = 0.f;
  if (tid < 2) *(float*)(Sp + 4194296 + 4 * tid) = 0.f;

  // reduce across the 16 lanes (l15) holding different codes of the same rows
#pragma unroll
  for (int m = 1; m < 16; m <<= 1) {
#pragma unroll
    for (int s = 0; s < 16; ++s) {
      float om = __shfl_xor(mn[s], m);
      int oi = __shfl_xor(mi[s], m);
      if (om < mn[s] || (om == mn[s] && oi < mi[s])) { mn[s] = om; mi[s] = oi; }
    }
  }
  if (l15 == 0) {
#pragma unroll
    for (int s = 0; s < 4; ++s)
#pragma unroll
      for (int r = 0; r < 4; ++r)
        { int lr = rg * 64 + s * 16 + kg * 4 + r;
          s_mn[cg][lr] = mn[s * 4 + r]; s_mi[cg][lr] = mi[s * 4 + r]; }
  }
  // drain this wave's zero stores; barrier => all waves' zeros ordered at L2
  // before any 1.0 one-hot store below.
  asm volatile("s_waitcnt vmcnt(0)" ::: "memory");
  __syncthreads();

  // merge 4 code-groups; one-hot 1.0 scatter; histogram; SSE partial
  if (tid < 128) {
    float bm = s_mn[0][tid]; int best = s_mi[0][tid];
#pragma unroll
    for (int c = 1; c < 4; ++c) {
      float m2 = s_mn[c][tid]; int i2 = s_mi[c][tid];
      if (m2 < bm || (m2 == bm && i2 < best)) { bm = m2; best = i2; }
    }
    s_mi[0][tid] = best;                       // publish for gather below
    s_red[tid] = bm + s_x2[tid];               // SSE(row) = dist + |x|^2
    enc[(size_t)(row0 + tid) * K_CODES + best] = 1.0f;
    atomicAdd(&counts[best], 1);
  }
  __syncthreads();
  for (int m = 64; m > 0; m >>= 1) {
    if (tid < m) s_red[tid] += s_red[tid + m];
    __syncthreads();
  }
  if (tid == 0) ssep[abid] = s_red[0];

  // quantized gather: one wave per 16 rows, coalesced plain scalar stores
  // (dest is 4B-aligned only: quant = out+1).
  for (int r = ww * 16; r < ww * 16 + 16; ++r) {
    int best = s_mi[0][r];
    float4 v = ((const float4*)(cb + (size_t)best * D_DIM))[lane];
    float* qp = quant + (size_t)(row0 + r) * D_DIM + lane * 4;
    qp[0] = v.x; qp[1] = v.y; qp[2] = v.z; qp[3] = v.w;
  }
}

// ---------------------------------------------------------------------------
// Finalize: vq_loss + perplexity (deterministic fixed-order reductions).
// ---------------------------------------------------------------------------
__global__ __launch_bounds__(256) void finalize_kernel(
    const float* __restrict__ ssep, const int* __restrict__ counts,
    float* __restrict__ out) {
  __shared__ float r1[256], r2[256];
  int t = threadIdx.x;
  float s1 = ssep[t];  // 256 argmin blocks, one partial each
  float s2 = 0.f;
  for (int j = 0; j < 32; ++j) {
    float p = (float)counts[t * 32 + j] * (1.0f / 32768.f);
    s2 += p * logf(p + 1e-10f);
  }
  r1[t] = s1; r2[t] = s2;
  __syncthreads();
  for (int m = 128; m > 0; m >>= 1) {
    if (t < m) { r1[t] += r1[t + m]; r2[t] += r2[t + m]; }
    __syncthreads();
  }
  if (t == 0) {
    out[0] = 1.25f * r1[0] / 8388608.f;   // q_latent + 0.25*e_latent
    out[8388609] = expf(-r2[0]);          // perplexity
  }
}

extern "C" void kernel_launch(void* const* d_in, const int* in_sizes, int n_in,
                              void* d_out, int out_size, void* d_ws, size_t ws_size,
                              hipStream_t stream) {
  const float* x = (const float*)d_in[0];
  const float* cb = (const float*)d_in[1];
  float* out = (float*)d_out;
  char* w = (char*)d_ws;
  unsigned short* ehw = (unsigned short*)(w);           // 128 * 33024 B = 4.03 MiB
  int* counts = (int*)(w + 4227072);                    // 32 KiB
  float* ssep = (float*)(w + 4259840);                  // 1 KiB

  float* quant = out + 1;
  float* enc = out + 8388610;

  eprep_kernel<<<K_CODES / 4, 256, 0, stream>>>(cb, ehw, counts);
  argmin_kernel<<<256, 512, 0, stream>>>(x, cb, ehw, quant, counts, ssep, enc);
  finalize_kernel<<<1, 256, 0, stream>>>(ssep, counts, out);
}

// Round 4
// 248.399 us; speedup vs baseline: 1.4408x; 1.4408x over previous
//
#include <hip/hip_runtime.h>
#include <stdint.h>

#define N_ROWS 32768
#define K_CODES 8192
#define D_DIM 256
#define STEP_BYTES 33024   // 32 KiB bf16 codes + 256 B fp32 c2 table (16B-aligned)
#define NBUF 4

typedef __attribute__((ext_vector_type(8))) short short8;
typedef __attribute__((ext_vector_type(4))) float f32x4;

__device__ __forceinline__ unsigned short f2bf_rne(float f) {
  union { float f; unsigned u; } v; v.f = f;
  unsigned r = v.u + 0x7fffu + ((v.u >> 16) & 1u);
  return (unsigned short)(r >> 16);
}

// ---------------------------------------------------------------------------
// Prep: codebook fp32 -> bf16 (RNE), XOR-swizzled within each 512B row.
// Each 64-code step tile carries a 256 B fp32 |e|^2 table (exact c2).
// Zeroes counts.
// ---------------------------------------------------------------------------
__global__ __launch_bounds__(256) void eprep_kernel(
    const float* __restrict__ cb, unsigned short* __restrict__ ehw,
    int* __restrict__ counts) {
  int w = threadIdx.x >> 6, lane = threadIdx.x & 63;
  int k = blockIdx.x * 4 + w;
  int gid = blockIdx.x * 256 + threadIdx.x;
  if (gid < K_CODES) counts[gid] = 0;
  const float4* src = (const float4*)(cb + (size_t)k * D_DIM);
  float4 v = src[lane];
  float vv[4] = {v.x, v.y, v.z, v.w};
  unsigned short h[4];
  float s = 0.f;
#pragma unroll
  for (int j = 0; j < 4; ++j) {
    float f = vv[j];
    s += f * f;
    h[j] = f2bf_rne(f);
  }
  char* stepb = (char*)ehw + (size_t)(k >> 6) * STEP_BYTES;
  int cl = k & 63;
  int off = (8 * lane) ^ ((k & 7) << 4);  // swizzle flips bits 4-6 only
  *(ushort4*)(stepb + cl * 512 + off) = make_ushort4(h[0], h[1], h[2], h[3]);
#pragma unroll
  for (int m = 1; m < 64; m <<= 1) s += __shfl_xor(s, m);
  if (lane == 0) *(float*)(stepb + 32768 + cl * 4) = s;  // fp32-exact |e|^2
}

// ---------------------------------------------------------------------------
// Argmin, T3+T4 counted-vmcnt pipeline (depth 3, 4 LDS buffers).
// R4 revision — single change vs R3: `nt` RESTORED on the zero stores.
//   R3 post-mortem: dropping nt made the 1.07 GB zero stream write-allocate
//   through the 4 MiB/XCD L2, evicting the shared ehw tiles (all 32
//   blocks/XCD re-read them every iter) -> 266->358 us. nt bypasses L2
//   allocation; alignment (R3's other, confounded change) is kept:
//   1024 B/instr dwordx4 = 8 full lines, no partial-line RMW.
// Layout: per-block enc region [S, S+4MiB), S == 8 (mod 128): head 120 B +
// tail 8 B via epilogue scalar stores; bulk = 128 aligned 32 KiB units,
// 4 dwordx4 nt stores/wave/iter interleaved into COMPUTE's MFMA channels.
// vmcnt stream: 5 loads + 4 stores per iter -> uniform wait vmcnt(18);
// tails 18/13/4. Final bulk unit is 120 B short: last store of wave 7 in
// peeled iter 125 is exec-predicated to lanes<56.
// 256 blocks x 128 rows; 8 waves = 2 row-groups x 4 code-groups.
// ---------------------------------------------------------------------------
__global__ __launch_bounds__(512, 1) void argmin_kernel(
    const float* __restrict__ x, const float* __restrict__ cb,
    const unsigned short* __restrict__ ehw,
    float* __restrict__ quant, int* __restrict__ counts,
    float* __restrict__ ssep, float* __restrict__ enc) {
  __shared__ __align__(16) char s_tiles[NBUF * STEP_BYTES];  // 129 KiB
  __shared__ float s_x2[128];
  __shared__ float s_red[128];
  // epilogue-only arrays aliased onto s_tiles (buf0 dead after the loop):
  float (*s_mn)[128] = (float (*)[128])(s_tiles);          // 2 KiB
  int (*s_mi)[128] = (int (*)[128])(s_tiles + 2048);       // 2 KiB

  const int tid = threadIdx.x;
  const int abid = blockIdx.x;
  const int ww = tid >> 6;
  const int lane = tid & 63;
  const int l15 = lane & 15;
  const int kg = lane >> 4;
  const int rg = ww >> 2;             // row group (0..1), 64 rows each
  const int cg = ww & 3;              // code group (0..3), 16 codes each
  const int row0 = abid * 128;

  auto STAGE = [&](int i, int b) {
    const char* g0 = (const char*)ehw + (size_t)i * STEP_BYTES + ww * 4096 + lane * 16;
    char* l0 = s_tiles + b * STEP_BYTES + ww * 4096;  // wave-uniform base
#pragma unroll
    for (int j = 0; j < 4; ++j) {
      __builtin_amdgcn_global_load_lds(
          (const __attribute__((address_space(1))) unsigned int*)(g0 + j * 1024),
          (__attribute__((address_space(3))) unsigned int*)(l0 + j * 1024), 16, 0, 0);
    }
    // c2 table: 256 B; ALL 8 waves load it redundantly (same data, same dest)
    // so every wave's vmcnt stream is a uniform 5 loads per stage.
    const char* g1 = (const char*)ehw + (size_t)i * STEP_BYTES + 32768 + lane * 4;
    char* l1 = s_tiles + b * STEP_BYTES + 32768;
    __builtin_amdgcn_global_load_lds(
        (const __attribute__((address_space(1))) unsigned int*)g1,
        (__attribute__((address_space(3))) unsigned int*)l1, 4, 0, 0);
  };

  // Aligned zero-fill bulk: unit u (u=0..127) = 32 KiB at S+120 + u*32768,
  // wave ww covers 4 KiB as 4 x dwordx4 nt (16 B/lane, full 128B lines).
  const f32x4 z4 = {0.f, 0.f, 0.f, 0.f};
  char* Sp = (char*)enc + (size_t)row0 * 32768;           // block region start
  char* zb = Sp + 120 + ww * 4096 + lane * 16;            // aligned bulk base
  auto ZST4 = [&](const char* p) {  // prologue burst form (4 stores)
    asm volatile(
        "global_store_dwordx4 %0, %1, off nt\n\t"
        "global_store_dwordx4 %0, %1, off offset:1024 nt\n\t"
        "global_store_dwordx4 %0, %1, off offset:2048 nt\n\t"
        "global_store_dwordx4 %0, %1, off offset:3072 nt"
        :: "v"(p), "v"(z4));
  };

  // prologue: S0 Z0 S1 Z1 S2 — uniform vmcnt(18) from iter 0.
  STAGE(0, 0); ZST4(zb); STAGE(1, 1); ZST4(zb + 32768); STAGE(2, 2);

  // load & convert A fragments: 64 rows/wave (4 subtiles of 16), bf16
  short8 a_h[4][8];
  float x2acc[4];
#pragma unroll
  for (int s = 0; s < 4; ++s) {
    const float* rp = x + (size_t)(row0 + rg * 64 + s * 16 + l15) * D_DIM + kg * 8;
    float s2 = 0.f;
#pragma unroll
    for (int ch = 0; ch < 8; ++ch) {
      const float4* p = (const float4*)(rp + ch * 32);
      float4 v0 = p[0], v1 = p[1];
      float f[8] = {v0.x, v0.y, v0.z, v0.w, v1.x, v1.y, v1.z, v1.w};
#pragma unroll
      for (int j = 0; j < 8; ++j) {
        s2 += f[j] * f[j];
        a_h[s][ch][j] = (short)f2bf_rne(f[j]);
      }
    }
    x2acc[s] = s2;
  }
#pragma unroll
  for (int s = 0; s < 4; ++s) {
    x2acc[s] += __shfl_xor(x2acc[s], 16);
    x2acc[s] += __shfl_xor(x2acc[s], 32);
  }
  if (cg == 0 && lane < 16) {  // kg==0 lanes
#pragma unroll
    for (int s = 0; s < 4; ++s) s_x2[rg * 64 + s * 16 + l15] = x2acc[s];
  }

  float mn[16];
  int mi[16];
#pragma unroll
  for (int s = 0; s < 16; ++s) { mn[s] = 3.4e38f; mi[s] = 0x7fffffff; }

  const int c_local = cg * 16 + l15;     // lane's code within the 64-code step
  const int rb = c_local * 512;
  const int xm = (l15 & 7) << 4;         // (code&7)<<4

  // COMPUTE: preload 8 vh (ds_read_b128) + scalar c2 (ds_read_b32 broadcast),
  // then 8 x [4 MFMA], with one aligned dwordx4 nt zero-store on even chans.
  // stmode: 0 = no stores, 1 = 4 stores, 2 = 4 stores w/ last predicated
  // (final unit is 120 B short -> wave 7 lanes 56..63 skip store j=3).
  auto COMPUTE = [&](int t, int stmode, const char* sp) {
    const char* bh = s_tiles + (t & 3) * STEP_BYTES;
    const int code = t * 64 + c_local;
    const float c2 = *(const float*)(bh + 32768 + c_local * 4);
    short8 vh[8];
#pragma unroll
    for (int ch = 0; ch < 8; ++ch)
      vh[ch] = *(const short8*)(bh + rb + ((ch * 64 + kg * 16) ^ xm));
    f32x4 acc[4];
#pragma unroll
    for (int s = 0; s < 4; ++s) acc[s] = (f32x4){0.f, 0.f, 0.f, 0.f};
#pragma unroll
    for (int ch = 0; ch < 8; ++ch) {
      if (stmode && (ch & 1) == 0) {
        const int j = ch >> 1;
        if (stmode == 1 || j < 3 || ww < 7 || lane < 56) {
          asm volatile("global_store_dwordx4 %0, %1, off nt"
                       :: "v"(sp + j * 1024), "v"(z4));
        }
      }
      acc[0] = __builtin_amdgcn_mfma_f32_16x16x32_bf16(a_h[0][ch], vh[ch], acc[0], 0, 0, 0);
      acc[1] = __builtin_amdgcn_mfma_f32_16x16x32_bf16(a_h[1][ch], vh[ch], acc[1], 0, 0, 0);
      acc[2] = __builtin_amdgcn_mfma_f32_16x16x32_bf16(a_h[2][ch], vh[ch], acc[2], 0, 0, 0);
      acc[3] = __builtin_amdgcn_mfma_f32_16x16x32_bf16(a_h[3][ch], vh[ch], acc[3], 0, 0, 0);
    }
#pragma unroll
    for (int s = 0; s < 4; ++s) {
#pragma unroll
      for (int r = 0; r < 4; ++r) {
        float d = __builtin_fmaf(-2.f, acc[s][r], c2);   // |e|^2 - 2 x.e
        if (d < mn[s * 4 + r]) { mn[s * 4 + r] = d; mi[s * 4 + r] = code; }
      }
    }
  };

  // iter t (0..124): zeroes unit t+2, stages tile t+3.
  // wait needs S_t done; younger ops = 2 iters x (4S+5L) = 18.
#pragma unroll 1
  for (int t = 0; t < 125; ++t) {
    asm volatile("s_waitcnt vmcnt(18)" ::: "memory");
    __builtin_amdgcn_s_barrier();
    __builtin_amdgcn_sched_barrier(0);
    COMPUTE(t, 1, zb + (size_t)(t + 2) * 32768);
    STAGE(t + 3, (t + 3) & 3);  // overwrites buf (t-1)&3: readers done at barrier
  }
  // t=125: zeroes final unit 127 (predicated last store), no stage.
  asm volatile("s_waitcnt vmcnt(18)" ::: "memory");
  __builtin_amdgcn_s_barrier();
  __builtin_amdgcn_sched_barrier(0);
  COMPUTE(125, 2, zb + (size_t)127 * 32768);
  // t=126: younger than S126 = Z126(4) + S127(5) + Z127(4) = 13.
  asm volatile("s_waitcnt vmcnt(13)" ::: "memory");
  __builtin_amdgcn_s_barrier();
  __builtin_amdgcn_sched_barrier(0);
  COMPUTE(126, 0, zb);
  // t=127: younger than S127 = Z127(4).
  asm volatile("s_waitcnt vmcnt(4)" ::: "memory");
  __builtin_amdgcn_s_barrier();
  __builtin_amdgcn_sched_barrier(0);
  COMPUTE(127, 0, zb);

  // head 120 B + tail 8 B of the block's enc region (mod-128 remainders)
  if (tid < 30) ((float*)Sp)[tid] = 0.f;
  if (tid < 2) *(float*)(Sp + 4194296 + 4 * tid) = 0.f;

  // reduce across the 16 lanes (l15) holding different codes of the same rows
#pragma unroll
  for (int m = 1; m < 16; m <<= 1) {
#pragma unroll
    for (int s = 0; s < 16; ++s) {
      float om = __shfl_xor(mn[s], m);
      int oi = __shfl_xor(mi[s], m);
      if (om < mn[s] || (om == mn[s] && oi < mi[s])) { mn[s] = om; mi[s] = oi; }
    }
  }
  if (l15 == 0) {
#pragma unroll
    for (int s = 0; s < 4; ++s)
#pragma unroll
      for (int r = 0; r < 4; ++r)
        { int lr = rg * 64 + s * 16 + kg * 4 + r;
          s_mn[cg][lr] = mn[s * 4 + r]; s_mi[cg][lr] = mi[s * 4 + r]; }
  }
  // drain this wave's zero stores; barrier => all waves' zeros ordered at L2
  // before any 1.0 one-hot store below.
  asm volatile("s_waitcnt vmcnt(0)" ::: "memory");
  __syncthreads();

  // merge 4 code-groups; one-hot 1.0 scatter; histogram; SSE partial
  if (tid < 128) {
    float bm = s_mn[0][tid]; int best = s_mi[0][tid];
#pragma unroll
    for (int c = 1; c < 4; ++c) {
      float m2 = s_mn[c][tid]; int i2 = s_mi[c][tid];
      if (m2 < bm || (m2 == bm && i2 < best)) { bm = m2; best = i2; }
    }
    s_mi[0][tid] = best;                       // publish for gather below
    s_red[tid] = bm + s_x2[tid];               // SSE(row) = dist + |x|^2
    enc[(size_t)(row0 + tid) * K_CODES + best] = 1.0f;
    atomicAdd(&counts[best], 1);
  }
  __syncthreads();
  for (int m = 64; m > 0; m >>= 1) {
    if (tid < m) s_red[tid] += s_red[tid + m];
    __syncthreads();
  }
  if (tid == 0) ssep[abid] = s_red[0];

  // quantized gather: one wave per 16 rows, coalesced plain scalar stores
  // (dest is 4B-aligned only: quant = out+1).
  for (int r = ww * 16; r < ww * 16 + 16; ++r) {
    int best = s_mi[0][r];
    float4 v = ((const float4*)(cb + (size_t)best * D_DIM))[lane];
    float* qp = quant + (size_t)(row0 + r) * D_DIM + lane * 4;
    qp[0] = v.x; qp[1] = v.y; qp[2] = v.z; qp[3] = v.w;
  }
}

// ---------------------------------------------------------------------------
// Finalize: vq_loss + perplexity (deterministic fixed-order reductions).
// ---------------------------------------------------------------------------
__global__ __launch_bounds__(256) void finalize_kernel(
    const float* __restrict__ ssep, const int* __restrict__ counts,
    float* __restrict__ out) {
  __shared__ float r1[256], r2[256];
  int t = threadIdx.x;
  float s1 = ssep[t];  // 256 argmin blocks, one partial each
  float s2 = 0.f;
  for (int j = 0; j < 32; ++j) {
    float p = (float)counts[t * 32 + j] * (1.0f / 32768.f);
    s2 += p * logf(p + 1e-10f);
  }
  r1[t] = s1; r2[t] = s2;
  __syncthreads();
  for (int m = 128; m > 0; m >>= 1) {
    if (t < m) { r1[t] += r1[t + m]; r2[t] += r2[t + m]; }
    __syncthreads();
  }
  if (t == 0) {
    out[0] = 1.25f * r1[0] / 8388608.f;   // q_latent + 0.25*e_latent
    out[8388609] = expf(-r2[0]);          // perplexity
  }
}

extern "C" void kernel_launch(void* const* d_in, const int* in_sizes, int n_in,
                              void* d_out, int out_size, void* d_ws, size_t ws_size,
                              hipStream_t stream) {
  const float* x = (const float*)d_in[0];
  const float* cb = (const float*)d_in[1];
  float* out = (float*)d_out;
  char* w = (char*)d_ws;
  unsigned short* ehw = (unsigned short*)(w);           // 128 * 33024 B = 4.03 MiB
  int* counts = (int*)(w + 4227072);                    // 32 KiB
  float* ssep = (float*)(w + 4259840);                  // 1 KiB

  float* quant = out + 1;
  float* enc = out + 8388610;

  eprep_kernel<<<K_CODES / 4, 256, 0, stream>>>(cb, ehw, counts);
  argmin_kernel<<<256, 512, 0, stream>>>(x, cb, ehw, quant, counts, ssep, enc);
  finalize_kernel<<<1, 256, 0, stream>>>(ssep, counts, out);
}

// Round 5
// 242.655 us; speedup vs baseline: 1.4749x; 1.0237x over previous
//
#include <hip/hip_runtime.h>
#include <stdint.h>

#define N_ROWS 32768
#define K_CODES 8192
#define D_DIM 256
#define STEP_BYTES 33024   // 32 KiB bf16 codes + 256 B fp32 c2 table (16B-aligned)
#define NBUF 4

typedef __attribute__((ext_vector_type(8))) short short8;
typedef __attribute__((ext_vector_type(4))) float f32x4;

__device__ __forceinline__ unsigned short f2bf_rne(float f) {
  union { float f; unsigned u; } v; v.f = f;
  unsigned r = v.u + 0x7fffu + ((v.u >> 16) & 1u);
  return (unsigned short)(r >> 16);
}

// ---------------------------------------------------------------------------
// Prep: codebook fp32 -> bf16 (RNE), XOR-swizzled within each 512B row.
// Each 64-code step tile carries a 256 B fp32 |e|^2 table (exact c2).
// Zeroes counts.
// ---------------------------------------------------------------------------
__global__ __launch_bounds__(256) void eprep_kernel(
    const float* __restrict__ cb, unsigned short* __restrict__ ehw,
    int* __restrict__ counts) {
  int w = threadIdx.x >> 6, lane = threadIdx.x & 63;
  int k = blockIdx.x * 4 + w;
  int gid = blockIdx.x * 256 + threadIdx.x;
  if (gid < K_CODES) counts[gid] = 0;
  const float4* src = (const float4*)(cb + (size_t)k * D_DIM);
  float4 v = src[lane];
  float vv[4] = {v.x, v.y, v.z, v.w};
  unsigned short h[4];
  float s = 0.f;
#pragma unroll
  for (int j = 0; j < 4; ++j) {
    float f = vv[j];
    s += f * f;
    h[j] = f2bf_rne(f);
  }
  char* stepb = (char*)ehw + (size_t)(k >> 6) * STEP_BYTES;
  int cl = k & 63;
  int off = (8 * lane) ^ ((k & 7) << 4);  // swizzle flips bits 4-6 only
  *(ushort4*)(stepb + cl * 512 + off) = make_ushort4(h[0], h[1], h[2], h[3]);
#pragma unroll
  for (int m = 1; m < 64; m <<= 1) s += __shfl_xor(s, m);
  if (lane == 0) *(float*)(stepb + 32768 + cl * 4) = s;  // fp32-exact |e|^2
}

// ---------------------------------------------------------------------------
// Argmin, T3+T4 counted-vmcnt pipeline (depth 3, 4 LDS buffers).
// R5 revision — single change vs R4: store stream decoupled by one more
// iteration. The in-order vmcnt counter means waiting for S_t also waits for
// every OLDER store to ack; R4 issued the Z stores (in COMPUTE) before
// STAGE, giving stores a 3-iter ack window and coupling loop advance to
// store acks. Now each iteration issues [COMPUTE (pure); STAGE(t+3);
// ZST4(unit t+3)] — stores are younger than the stage they ride with, so
// the wait for S_t excludes same-age stores: slack 3->4 iterations, wait
// vmcnt(22) (= Z,S,Z,S,Z younger than S_t). Prologue S0 Z0 S1 Z1 S2 Z2
// keeps the count uniform from iter 0. Tails 22/13/4. Final unit (#127,
// 120 B short) rides peeled iter 124 with the last store exec-predicated.
// 256 blocks x 128 rows; 8 waves = 2 row-groups x 4 code-groups.
// ---------------------------------------------------------------------------
__global__ __launch_bounds__(512, 1) void argmin_kernel(
    const float* __restrict__ x, const float* __restrict__ cb,
    const unsigned short* __restrict__ ehw,
    float* __restrict__ quant, int* __restrict__ counts,
    float* __restrict__ ssep, float* __restrict__ enc) {
  __shared__ __align__(16) char s_tiles[NBUF * STEP_BYTES];  // 129 KiB
  __shared__ float s_x2[128];
  __shared__ float s_red[128];
  // epilogue-only arrays aliased onto s_tiles (buf0 dead after the loop):
  float (*s_mn)[128] = (float (*)[128])(s_tiles);          // 2 KiB
  int (*s_mi)[128] = (int (*)[128])(s_tiles + 2048);       // 2 KiB

  const int tid = threadIdx.x;
  const int abid = blockIdx.x;
  const int ww = tid >> 6;
  const int lane = tid & 63;
  const int l15 = lane & 15;
  const int kg = lane >> 4;
  const int rg = ww >> 2;             // row group (0..1), 64 rows each
  const int cg = ww & 3;              // code group (0..3), 16 codes each
  const int row0 = abid * 128;

  auto STAGE = [&](int i, int b) {
    const char* g0 = (const char*)ehw + (size_t)i * STEP_BYTES + ww * 4096 + lane * 16;
    char* l0 = s_tiles + b * STEP_BYTES + ww * 4096;  // wave-uniform base
#pragma unroll
    for (int j = 0; j < 4; ++j) {
      __builtin_amdgcn_global_load_lds(
          (const __attribute__((address_space(1))) unsigned int*)(g0 + j * 1024),
          (__attribute__((address_space(3))) unsigned int*)(l0 + j * 1024), 16, 0, 0);
    }
    // c2 table: 256 B; ALL 8 waves load it redundantly (same data, same dest)
    // so every wave's vmcnt stream is a uniform 5 loads per stage.
    const char* g1 = (const char*)ehw + (size_t)i * STEP_BYTES + 32768 + lane * 4;
    char* l1 = s_tiles + b * STEP_BYTES + 32768;
    __builtin_amdgcn_global_load_lds(
        (const __attribute__((address_space(1))) unsigned int*)g1,
        (__attribute__((address_space(3))) unsigned int*)l1, 4, 0, 0);
  };

  // Aligned zero-fill bulk: unit u (u=0..127) = 32 KiB at S+120 + u*32768,
  // wave ww covers 4 KiB as 4 x dwordx4 nt (16 B/lane, full 128B lines).
  const f32x4 z4 = {0.f, 0.f, 0.f, 0.f};
  char* Sp = (char*)enc + (size_t)row0 * 32768;           // block region start
  char* zb = Sp + 120 + ww * 4096 + lane * 16;            // aligned bulk base
  auto ZST4 = [&](const char* p) {  // 4 nt stores, 1024 B apart
    asm volatile(
        "global_store_dwordx4 %0, %1, off nt\n\t"
        "global_store_dwordx4 %0, %1, off offset:1024 nt\n\t"
        "global_store_dwordx4 %0, %1, off offset:2048 nt\n\t"
        "global_store_dwordx4 %0, %1, off offset:3072 nt"
        :: "v"(p), "v"(z4));
  };
  // Final-unit variant: unit 127 is 120 B short -> wave 7 lanes>=56 skip the
  // last store. Still 4 vmem ops per wave (exec-masked, never empty).
  auto ZST4P = [&](const char* p) {
    asm volatile(
        "global_store_dwordx4 %0, %1, off nt\n\t"
        "global_store_dwordx4 %0, %1, off offset:1024 nt\n\t"
        "global_store_dwordx4 %0, %1, off offset:2048 nt"
        :: "v"(p), "v"(z4));
    if (ww < 7 || lane < 56) {
      asm volatile("global_store_dwordx4 %0, %1, off offset:3072 nt"
                   :: "v"(p), "v"(z4));
    }
  };

  // prologue: S0 Z0 S1 Z1 S2 Z2 — younger-than-S0 = 22 from iter 0.
  STAGE(0, 0); ZST4(zb);
  STAGE(1, 1); ZST4(zb + 32768);
  STAGE(2, 2); ZST4(zb + 2 * 32768);

  // load & convert A fragments: 64 rows/wave (4 subtiles of 16), bf16
  short8 a_h[4][8];
  float x2acc[4];
#pragma unroll
  for (int s = 0; s < 4; ++s) {
    const float* rp = x + (size_t)(row0 + rg * 64 + s * 16 + l15) * D_DIM + kg * 8;
    float s2 = 0.f;
#pragma unroll
    for (int ch = 0; ch < 8; ++ch) {
      const float4* p = (const float4*)(rp + ch * 32);
      float4 v0 = p[0], v1 = p[1];
      float f[8] = {v0.x, v0.y, v0.z, v0.w, v1.x, v1.y, v1.z, v1.w};
#pragma unroll
      for (int j = 0; j < 8; ++j) {
        s2 += f[j] * f[j];
        a_h[s][ch][j] = (short)f2bf_rne(f[j]);
      }
    }
    x2acc[s] = s2;
  }
#pragma unroll
  for (int s = 0; s < 4; ++s) {
    x2acc[s] += __shfl_xor(x2acc[s], 16);
    x2acc[s] += __shfl_xor(x2acc[s], 32);
  }
  if (cg == 0 && lane < 16) {  // kg==0 lanes
#pragma unroll
    for (int s = 0; s < 4; ++s) s_x2[rg * 64 + s * 16 + l15] = x2acc[s];
  }

  float mn[16];
  int mi[16];
#pragma unroll
  for (int s = 0; s < 16; ++s) { mn[s] = 3.4e38f; mi[s] = 0x7fffffff; }

  const int c_local = cg * 16 + l15;     // lane's code within the 64-code step
  const int rb = c_local * 512;
  const int xm = (l15 & 7) << 4;         // (code&7)<<4

  // COMPUTE (pure): preload 8 vh (ds_read_b128) + scalar c2 (ds_read_b32
  // broadcast), 32 MFMA, min-update.
  auto COMPUTE = [&](int t) {
    const char* bh = s_tiles + (t & 3) * STEP_BYTES;
    const int code = t * 64 + c_local;
    const float c2 = *(const float*)(bh + 32768 + c_local * 4);
    short8 vh[8];
#pragma unroll
    for (int ch = 0; ch < 8; ++ch)
      vh[ch] = *(const short8*)(bh + rb + ((ch * 64 + kg * 16) ^ xm));
    f32x4 acc[4];
#pragma unroll
    for (int s = 0; s < 4; ++s) acc[s] = (f32x4){0.f, 0.f, 0.f, 0.f};
#pragma unroll
    for (int ch = 0; ch < 8; ++ch) {
      acc[0] = __builtin_amdgcn_mfma_f32_16x16x32_bf16(a_h[0][ch], vh[ch], acc[0], 0, 0, 0);
      acc[1] = __builtin_amdgcn_mfma_f32_16x16x32_bf16(a_h[1][ch], vh[ch], acc[1], 0, 0, 0);
      acc[2] = __builtin_amdgcn_mfma_f32_16x16x32_bf16(a_h[2][ch], vh[ch], acc[2], 0, 0, 0);
      acc[3] = __builtin_amdgcn_mfma_f32_16x16x32_bf16(a_h[3][ch], vh[ch], acc[3], 0, 0, 0);
    }
#pragma unroll
    for (int s = 0; s < 4; ++s) {
#pragma unroll
      for (int r = 0; r < 4; ++r) {
        float d = __builtin_fmaf(-2.f, acc[s][r], c2);   // |e|^2 - 2 x.e
        if (d < mn[s * 4 + r]) { mn[s * 4 + r] = d; mi[s * 4 + r] = code; }
      }
    }
  };

  // iter t: COMPUTE tile t, stage tile t+3, zero unit t+3.
  // wait needs S_t acked; ops younger than S_t = Z_t(4) + S_{t+1}(5) +
  // Z_{t+1}(4) + S_{t+2}(5) + Z_{t+2}(4) = 22. Stores issued in iter u
  // must ack only by top of iter u+4 (4-iteration slack).
#pragma unroll 1
  for (int t = 0; t < 124; ++t) {
    asm volatile("s_waitcnt vmcnt(22)" ::: "memory");
    __builtin_amdgcn_s_barrier();
    __builtin_amdgcn_sched_barrier(0);
    COMPUTE(t);
    STAGE(t + 3, (t + 3) & 3);  // overwrites buf (t-1)&3: readers done at barrier
    ZST4(zb + (size_t)(t + 3) * 32768);
  }
  // t=124: stages tile 127, zeroes final unit 127 (predicated last store).
  asm volatile("s_waitcnt vmcnt(22)" ::: "memory");
  __builtin_amdgcn_s_barrier();
  __builtin_amdgcn_sched_barrier(0);
  COMPUTE(124);
  STAGE(127, 127 & 3);
  ZST4P(zb + (size_t)127 * 32768);
  // t=125: younger than S_125 = Z125u(4)+S126(5)+Z126u(4)+S127(5)+Z127u(4)=22.
  asm volatile("s_waitcnt vmcnt(22)" ::: "memory");
  __builtin_amdgcn_s_barrier();
  __builtin_amdgcn_sched_barrier(0);
  COMPUTE(125);
  // t=126: younger than S_126 = Z126u(4)+S127(5)+Z127u(4) = 13.
  asm volatile("s_waitcnt vmcnt(13)" ::: "memory");
  __builtin_amdgcn_s_barrier();
  __builtin_amdgcn_sched_barrier(0);
  COMPUTE(126);
  // t=127: younger than S_127 = Z127u(4).
  asm volatile("s_waitcnt vmcnt(4)" ::: "memory");
  __builtin_amdgcn_s_barrier();
  __builtin_amdgcn_sched_barrier(0);
  COMPUTE(127);

  // head 120 B + tail 8 B of the block's enc region (mod-128 remainders)
  if (tid < 30) ((float*)Sp)[tid] = 0.f;
  if (tid < 2) *(float*)(Sp + 4194296 + 4 * tid) = 0.f;

  // reduce across the 16 lanes (l15) holding different codes of the same rows
#pragma unroll
  for (int m = 1; m < 16; m <<= 1) {
#pragma unroll
    for (int s = 0; s < 16; ++s) {
      float om = __shfl_xor(mn[s], m);
      int oi = __shfl_xor(mi[s], m);
      if (om < mn[s] || (om == mn[s] && oi < mi[s])) { mn[s] = om; mi[s] = oi; }
    }
  }
  if (l15 == 0) {
#pragma unroll
    for (int s = 0; s < 4; ++s)
#pragma unroll
      for (int r = 0; r < 4; ++r)
        { int lr = rg * 64 + s * 16 + kg * 4 + r;
          s_mn[cg][lr] = mn[s * 4 + r]; s_mi[cg][lr] = mi[s * 4 + r]; }
  }
  // drain this wave's zero stores; barrier => all waves' zeros ordered at L2
  // before any 1.0 one-hot store below.
  asm volatile("s_waitcnt vmcnt(0)" ::: "memory");
  __syncthreads();

  // merge 4 code-groups; one-hot 1.0 scatter; histogram; SSE partial
  if (tid < 128) {
    float bm = s_mn[0][tid]; int best = s_mi[0][tid];
#pragma unroll
    for (int c = 1; c < 4; ++c) {
      float m2 = s_mn[c][tid]; int i2 = s_mi[c][tid];
      if (m2 < bm || (m2 == bm && i2 < best)) { bm = m2; best = i2; }
    }
    s_mi[0][tid] = best;                       // publish for gather below
    s_red[tid] = bm + s_x2[tid];               // SSE(row) = dist + |x|^2
    enc[(size_t)(row0 + tid) * K_CODES + best] = 1.0f;
    atomicAdd(&counts[best], 1);
  }
  __syncthreads();
  for (int m = 64; m > 0; m >>= 1) {
    if (tid < m) s_red[tid] += s_red[tid + m];
    __syncthreads();
  }
  if (tid == 0) ssep[abid] = s_red[0];

  // quantized gather: one wave per 16 rows, coalesced plain scalar stores
  // (dest is 4B-aligned only: quant = out+1).
  for (int r = ww * 16; r < ww * 16 + 16; ++r) {
    int best = s_mi[0][r];
    float4 v = ((const float4*)(cb + (size_t)best * D_DIM))[lane];
    float* qp = quant + (size_t)(row0 + r) * D_DIM + lane * 4;
    qp[0] = v.x; qp[1] = v.y; qp[2] = v.z; qp[3] = v.w;
  }
}

// ---------------------------------------------------------------------------
// Finalize: vq_loss + perplexity (deterministic fixed-order reductions).
// ---------------------------------------------------------------------------
__global__ __launch_bounds__(256) void finalize_kernel(
    const float* __restrict__ ssep, const int* __restrict__ counts,
    float* __restrict__ out) {
  __shared__ float r1[256], r2[256];
  int t = threadIdx.x;
  float s1 = ssep[t];  // 256 argmin blocks, one partial each
  float s2 = 0.f;
  for (int j = 0; j < 32; ++j) {
    float p = (float)counts[t * 32 + j] * (1.0f / 32768.f);
    s2 += p * logf(p + 1e-10f);
  }
  r1[t] = s1; r2[t] = s2;
  __syncthreads();
  for (int m = 128; m > 0; m >>= 1) {
    if (t < m) { r1[t] += r1[t + m]; r2[t] += r2[t + m]; }
    __syncthreads();
  }
  if (t == 0) {
    out[0] = 1.25f * r1[0] / 8388608.f;   // q_latent + 0.25*e_latent
    out[8388609] = expf(-r2[0]);          // perplexity
  }
}

extern "C" void kernel_launch(void* const* d_in, const int* in_sizes, int n_in,
                              void* d_out, int out_size, void* d_ws, size_t ws_size,
                              hipStream_t stream) {
  const float* x = (const float*)d_in[0];
  const float* cb = (const float*)d_in[1];
  float* out = (float*)d_out;
  char* w = (char*)d_ws;
  unsigned short* ehw = (unsigned short*)(w);           // 128 * 33024 B = 4.03 MiB
  int* counts = (int*)(w + 4227072);                    // 32 KiB
  float* ssep = (float*)(w + 4259840);                  // 1 KiB

  float* quant = out + 1;
  float* enc = out + 8388610;

  eprep_kernel<<<K_CODES / 4, 256, 0, stream>>>(cb, ehw, counts);
  argmin_kernel<<<256, 512, 0, stream>>>(x, cb, ehw, quant, counts, ssep, enc);
  finalize_kernel<<<1, 256, 0, stream>>>(ssep, counts, out);
}